// Round 8
// baseline (355.672 us; speedup 1.0000x reference)
//
#include <hip/hip_runtime.h>

typedef __attribute__((ext_vector_type(8))) short short8;
typedef __attribute__((ext_vector_type(4))) float f32x4;
typedef __attribute__((ext_vector_type(4))) unsigned uint4v;

__device__ __forceinline__ void gload_lds16(const void* g, void* l) {
    __builtin_amdgcn_global_load_lds(
        (const __attribute__((address_space(1))) unsigned*)g,
        (__attribute__((address_space(3))) unsigned*)l, 16, 0, 0);
}
#define MFMA16(a, b, c) __builtin_amdgcn_mfma_f32_16x16x32_bf16((a), (b), (c), 0, 0, 0)

// ---------------------------------------------------------------------------
// fp32 GEMM (R7-verified): BM=32 BN=32 BK=32, 256 thr, 1x4 microtile.
// Used ONLY for enc1 (+ fused w2 transpose/split side-job on blockIdx.y>=32).
// ---------------------------------------------------------------------------
template<bool RELU, bool LNA, bool SPLITW2>
__global__ __launch_bounds__(256)
void gemm_s(const float* __restrict__ A,
            const float* __restrict__ B0, const float* __restrict__ bias0,
            float* __restrict__ C0,
            const float* __restrict__ B1, const float* __restrict__ bias1,
            float* __restrict__ C1,
            const float* __restrict__ ps, const float* __restrict__ lg,
            const float* __restrict__ lb,
            int M, int N, int K, int nxHalf,
            const float* __restrict__ w2, short* __restrict__ w2th,
            short* __restrict__ w2tl)
{
    if (SPLITW2 && blockIdx.y >= 32) {
        int e = ((blockIdx.y - 32) * gridDim.x + blockIdx.x) * 256 + threadIdx.x;
        if (e < 32768) {
            int k = e >> 7, n = e & 127;
            float x = w2[e];
            unsigned hu = __float_as_uint(x) & 0xFFFF0000u;
            w2th[n * 256 + k] = (short)(hu >> 16);
            w2tl[n * 256 + k] = (short)(__float_as_uint(x - __uint_as_float(hu)) >> 16);
        }
        return;
    }
    int bx = blockIdx.x;
    const float* B = B0; const float* bias = bias0; float* C = C0;
    if (nxHalf && bx >= nxHalf) { bx -= nxHalf; B = B1; bias = bias1; C = C1; }
    const int m0 = blockIdx.y * 32, n0 = bx * 32;
    const int tid = threadIdx.x;
    const int tx = tid & 7, ty = tid >> 3;

    __shared__ __align__(16) float As[32 * 36];
    __shared__ __align__(16) float Bs[32 * 36];

    float acc[4] = {};
    for (int k0 = 0; k0 < K; k0 += 32) {
        {
            int row = ty, kq = tx << 2;
            float4 v = *(const float4*)&A[(long)(m0 + row) * K + k0 + kq];
            As[(kq + 0) * 36 + row] = v.x; As[(kq + 1) * 36 + row] = v.y;
            As[(kq + 2) * 36 + row] = v.z; As[(kq + 3) * 36 + row] = v.w;
        }
        *(float4*)&Bs[ty * 36 + tx * 4] =
            *(const float4*)&B[(long)(k0 + ty) * N + n0 + tx * 4];
        __syncthreads();
#pragma unroll
        for (int k = 0; k < 32; ++k) {
            float a = As[k * 36 + ty];
            float4 b4 = *(const float4*)&Bs[k * 36 + tx * 4];
            acc[0] += a * b4.x; acc[1] += a * b4.y;
            acc[2] += a * b4.z; acc[3] += a * b4.w;
        }
        __syncthreads();
    }

    int m = m0 + ty;
#pragma unroll
    for (int j = 0; j < 4; ++j) {
        int n = n0 + tx * 4 + j;
        float v = acc[j];
        if (bias) v += bias[n];
        if (RELU) v = fmaxf(v, 0.f);
        C[(long)m * N + n] = v;
    }
}

// ---------------------------------------------------------------------------
// enc2_fuse: per block, 4 complete rows.
//   xe = h1 @ ew2 + eb2          (K=512)
//   eg0 = xe @ wedge[0] + bedge[0]  (K=256)
// 256 threads: wave r (=tid>>6) owns row r; thread covers cols cg*4..+3.
// W rows read coalesced (1KB/inst) straight from L2.
// ---------------------------------------------------------------------------
__global__ __launch_bounds__(256)
void enc2_fuse(const float* __restrict__ h1, const float* __restrict__ ew2,
               const float* __restrict__ eb2, const float* __restrict__ we0,
               const float* __restrict__ be0, float* __restrict__ xe,
               float* __restrict__ eg0)
{
    const int tid = threadIdx.x;
    const int gr0 = blockIdx.x * 4;
    const int r = tid >> 6, cg = (tid & 63) * 4;
    __shared__ __align__(16) float hs[4][512];
    __shared__ __align__(16) float xs[4][256];
    {
        int k0 = (tid & 63) * 8;
        *(float4*)&hs[r][k0]     = *(const float4*)&h1[(long)(gr0 + r) * 512 + k0];
        *(float4*)&hs[r][k0 + 4] = *(const float4*)&h1[(long)(gr0 + r) * 512 + k0 + 4];
    }
    __syncthreads();

    float4 o = {0.f, 0.f, 0.f, 0.f};
#pragma unroll 8
    for (int k = 0; k < 512; ++k) {
        float4 w = *(const float4*)&ew2[(long)k * 256 + cg];
        float a = hs[r][k];
        o.x += a * w.x; o.y += a * w.y; o.z += a * w.z; o.w += a * w.w;
    }
    float4 bv = *(const float4*)&eb2[cg];
    o.x += bv.x; o.y += bv.y; o.z += bv.z; o.w += bv.w;
    *(float4*)&xs[r][cg] = o;
    *(float4*)&xe[(long)(gr0 + r) * 256 + cg] = o;
    __syncthreads();

    float4 e = {0.f, 0.f, 0.f, 0.f};
#pragma unroll 8
    for (int k = 0; k < 256; ++k) {
        float4 w = *(const float4*)&we0[(long)k * 256 + cg];
        float a = xs[r][k];
        e.x += a * w.x; e.y += a * w.y; e.z += a * w.z; e.w += a * w.w;
    }
    float4 be = *(const float4*)&be0[cg];
    e.x += be.x; e.y += be.y; e.z += be.z; e.w += be.w;
    *(float4*)&eg0[(long)(gr0 + r) * 256 + cg] = e;
}

// ---------------------------------------------------------------------------
// layer_fuse<LAST>: per block, 4 complete rows of one GCN layer:
//   ng = bp @ eg_in   (eg complete from previous dispatch)
//   sf = h_in @ Ws + bs
//   x  = relu(sf + ng);  LN stats per row = ONE wave shfl reduce
//   h' = LN(x)*g + b    -> h_out (and LDS)
//   !LAST: out0 = h' @ Wn0 + bn0   (eg for next layer)
//   LAST : out0 = h' @ Wn0 (hi),  out1 = h' @ Wn1 (hj)   (no bias)
// ---------------------------------------------------------------------------
template<bool LAST>
__global__ __launch_bounds__(256)
void layer_fuse(const float* __restrict__ h_in, const float* __restrict__ bp,
                const float* __restrict__ eg_in,
                const float* __restrict__ Ws, const float* __restrict__ bs,
                const float* __restrict__ lg, const float* __restrict__ lb,
                const float* __restrict__ Wn0, const float* __restrict__ bn0,
                const float* __restrict__ Wn1,
                float* __restrict__ h_out, float* __restrict__ out0,
                float* __restrict__ out1)
{
    const int tid = threadIdx.x;
    const int gr0 = blockIdx.x * 4;
    const int b = gr0 >> 8;
    const float* egb = eg_in + (long)b * 65536;
    const int r = tid >> 6, cg = (tid & 63) * 4;
    __shared__ __align__(16) float hs[4][256];
    __shared__ __align__(16) float ps[4][256];
    {
        int k0 = (tid & 63) * 4;
        *(float4*)&hs[r][k0] = *(const float4*)&h_in[(long)(gr0 + r) * 256 + k0];
        *(float4*)&ps[r][k0] = *(const float4*)&bp[(long)(gr0 + r) * 256 + k0];
    }
    __syncthreads();

    // fused dual GEMM: ng (A=bp rows, W=eg) + sf (A=h rows, W=Ws)
    float4 ng = {0.f, 0.f, 0.f, 0.f}, sf = {0.f, 0.f, 0.f, 0.f};
#pragma unroll 4
    for (int k = 0; k < 256; ++k) {
        float4 we = *(const float4*)&egb[(long)k * 256 + cg];
        float4 ws = *(const float4*)&Ws[(long)k * 256 + cg];
        float ap = ps[r][k];
        float ah = hs[r][k];
        ng.x += ap * we.x; ng.y += ap * we.y; ng.z += ap * we.z; ng.w += ap * we.w;
        sf.x += ah * ws.x; sf.y += ah * ws.y; sf.z += ah * ws.z; sf.w += ah * ws.w;
    }
    float4 bsv = *(const float4*)&bs[cg];
    float x0 = fmaxf(sf.x + bsv.x + ng.x, 0.f);
    float x1 = fmaxf(sf.y + bsv.y + ng.y, 0.f);
    float x2 = fmaxf(sf.z + bsv.z + ng.z, 0.f);
    float x3 = fmaxf(sf.w + bsv.w + ng.w, 0.f);

    // per-row LN stats: wave r holds the entire row
    float s = x0 + x1 + x2 + x3;
    float s2 = x0 * x0 + x1 * x1 + x2 * x2 + x3 * x3;
#pragma unroll
    for (int off = 1; off < 64; off <<= 1) {
        s  += __shfl_xor(s,  off, 64);
        s2 += __shfl_xor(s2, off, 64);
    }
    const float mu  = s * (1.f / 256.f);
    const float var = s2 * (1.f / 256.f) - mu * mu;
    const float rsv = rsqrtf(var + 1e-5f);
    float4 gv = *(const float4*)&lg[cg];
    float4 bbv = *(const float4*)&lb[cg];
    float4 xl;
    xl.x = (x0 - mu) * rsv * gv.x + bbv.x;
    xl.y = (x1 - mu) * rsv * gv.y + bbv.y;
    xl.z = (x2 - mu) * rsv * gv.z + bbv.z;
    xl.w = (x3 - mu) * rsv * gv.w + bbv.w;

    __syncthreads();               // all hs/ps reads complete
    *(float4*)&hs[r][cg] = xl;     // republish h' in LDS
    if (!LAST)
        *(float4*)&h_out[(long)(gr0 + r) * 256 + cg] = xl;
    __syncthreads();

    // next-layer edge GEMM (or hi for LAST)
    float4 a0 = {0.f, 0.f, 0.f, 0.f};
#pragma unroll 8
    for (int k = 0; k < 256; ++k) {
        float4 w = *(const float4*)&Wn0[(long)k * 256 + cg];
        float a = hs[r][k];
        a0.x += a * w.x; a0.y += a * w.y; a0.z += a * w.z; a0.w += a * w.w;
    }
    if (!LAST) {
        float4 bn = *(const float4*)&bn0[cg];
        a0.x += bn.x; a0.y += bn.y; a0.z += bn.z; a0.w += bn.w;
        *(float4*)&out0[(long)(gr0 + r) * 256 + cg] = a0;
    } else {
        *(float4*)&out0[(long)(gr0 + r) * 256 + cg] = a0;   // hi (no bias)
        float4 a1 = {0.f, 0.f, 0.f, 0.f};
#pragma unroll 8
        for (int k = 0; k < 256; ++k) {
            float4 w = *(const float4*)&Wn1[(long)k * 256 + cg];
            float a = hs[r][k];
            a1.x += a * w.x; a1.y += a * w.y; a1.z += a * w.z; a1.w += a * w.w;
        }
        *(float4*)&out1[(long)(gr0 + r) * 256 + cg] = a1;   // hj (no bias)
    }
}

// ---------------------------------------------------------------------------
// Pairwise scorer v4 (R7-verified, byte-identical): all-b128 LDS traffic,
// double-buffered P, ONE barrier per k-tile, MFMA bf16 3-pass hi/lo.
// ---------------------------------------------------------------------------
#define STAGE_HJ(T, BUF)                                                        \
    {                                                                           \
        int row = tid >> 3, s = tid & 7;                                        \
        gload_lds16(&hja[((long)(b * 256 + j0 + row)) * 256 + (T) * 32          \
                         + ((s ^ (row & 7)) << 2)],                             \
                    (char*)&hjs[BUF][0] + tid * 16);                            \
        int row2 = row + 32;                                                    \
        gload_lds16(&hja[((long)(b * 256 + j0 + row2)) * 256 + (T) * 32         \
                         + ((s ^ (row2 & 7)) << 2)],                            \
                    (char*)&hjs[BUF][0] + 4096 + tid * 16);                     \
    }

#define BUILD_P(KT, BUF)                                                        \
    {                                                                           \
        const char* hbase = (const char*)&hjs[BUF][0] + jj * 128;               \
        char* phc = (char*)&Ph[BUF][0];                                         \
        char* plc = (char*)&Pl[BUF][0];                                         \
        const int swz = (p & 7) << 4;                                           \
        _Pragma("unroll")                                                       \
        for (int q = 0; q < 2; ++q) {                                           \
            const int oct = o0 + q;                                             \
            float4 hv0 = *(const float4*)(hbase + (((oct * 2)     ^ (jj & 7)) << 4)); \
            float4 hv1 = *(const float4*)(hbase + (((oct * 2 + 1) ^ (jj & 7)) << 4)); \
            float4 iv0 = *(const float4*)&hib[ii][(KT) * 32 + oct * 8];         \
            float4 iv1 = *(const float4*)&hib[ii][(KT) * 32 + oct * 8 + 4];     \
            float4 cv0 = *(const float4*)&csv[(KT) * 32 + oct * 8];             \
            float4 cv1 = *(const float4*)&csv[(KT) * 32 + oct * 8 + 4];         \
            float x0 = fmaxf(fmaf(bpw, cv0.x, iv0.x) + hv0.x, 0.f);             \
            float x1 = fmaxf(fmaf(bpw, cv0.y, iv0.y) + hv0.y, 0.f);             \
            float x2 = fmaxf(fmaf(bpw, cv0.z, iv0.z) + hv0.z, 0.f);             \
            float x3 = fmaxf(fmaf(bpw, cv0.w, iv0.w) + hv0.w, 0.f);             \
            float x4 = fmaxf(fmaf(bpw, cv1.x, iv1.x) + hv1.x, 0.f);             \
            float x5 = fmaxf(fmaf(bpw, cv1.y, iv1.y) + hv1.y, 0.f);             \
            float x6 = fmaxf(fmaf(bpw, cv1.z, iv1.z) + hv1.z, 0.f);             \
            float x7 = fmaxf(fmaf(bpw, cv1.w, iv1.w) + hv1.w, 0.f);             \
            unsigned h0 = __float_as_uint(x0) & 0xFFFF0000u;                    \
            unsigned h1 = __float_as_uint(x1) & 0xFFFF0000u;                    \
            unsigned h2 = __float_as_uint(x2) & 0xFFFF0000u;                    \
            unsigned h3 = __float_as_uint(x3) & 0xFFFF0000u;                    \
            unsigned h4 = __float_as_uint(x4) & 0xFFFF0000u;                    \
            unsigned h5 = __float_as_uint(x5) & 0xFFFF0000u;                    \
            unsigned h6 = __float_as_uint(x6) & 0xFFFF0000u;                    \
            unsigned h7 = __float_as_uint(x7) & 0xFFFF0000u;                    \
            uint4v hv_, lv_;                                                    \
            hv_[0] = (h0 >> 16) | h1;                                           \
            hv_[1] = (h2 >> 16) | h3;                                           \
            hv_[2] = (h4 >> 16) | h5;                                           \
            hv_[3] = (h6 >> 16) | h7;                                           \
            lv_[0] = (__float_as_uint(x0 - __uint_as_float(h0)) >> 16)          \
                   | (__float_as_uint(x1 - __uint_as_float(h1)) & 0xFFFF0000u); \
            lv_[1] = (__float_as_uint(x2 - __uint_as_float(h2)) >> 16)          \
                   | (__float_as_uint(x3 - __uint_as_float(h3)) & 0xFFFF0000u); \
            lv_[2] = (__float_as_uint(x4 - __uint_as_float(h4)) >> 16)          \
                   | (__float_as_uint(x5 - __uint_as_float(h5)) & 0xFFFF0000u); \
            lv_[3] = (__float_as_uint(x6 - __uint_as_float(h6)) >> 16)          \
                   | (__float_as_uint(x7 - __uint_as_float(h7)) & 0xFFFF0000u); \
            int sbyte = p * 64 + oct * 16;                                      \
            *(uint4v*)(phc + (sbyte ^ swz)) = hv_;                              \
            *(uint4v*)(plc + (sbyte ^ swz)) = lv_;                              \
        }                                                                       \
    }

__global__ __launch_bounds__(256, 3)
void pairwise4(const float* __restrict__ hia, const float* __restrict__ hja,
               const float* __restrict__ bpm,
               const float* __restrict__ c, const float* __restrict__ b1,
               const short* __restrict__ w2th, const short* __restrict__ w2tl,
               const float* __restrict__ b2, const float* __restrict__ w3,
               const float* __restrict__ b3, float* __restrict__ out)
{
    const int b = blockIdx.z, ib0 = blockIdx.y * 2, j0 = blockIdx.x * 64;
    const int tid = threadIdx.x, l = tid & 63, wid = tid >> 6;
    const int wm0 = (wid & 1) * 64, wn0 = (wid >> 1) * 64;
    const int g = l >> 4, ln = l & 15;
    const int p = tid >> 1, jj = p & 63, ii = p >> 6, o0 = (tid & 1) * 2;

    __shared__ __align__(16) short Ph[2][4096];
    __shared__ __align__(16) short Pl[2][4096];
    __shared__ __align__(16) float hjs[2][2048];
    __shared__ __align__(16) float hib[2][256];
    __shared__ __align__(16) float csv[256];
    __shared__ float bpv[128];
    __shared__ float red[128][2];

    if (tid < 128)
        bpv[tid] = bpm[((long)(b * 256 + ib0 + (tid >> 6))) * 256 + j0 + (tid & 63)];
    {
        int i2 = tid >> 7, kk = (tid & 127) * 2;
        float2 hv = *(const float2*)&hia[((long)(b * 256 + ib0 + i2)) * 256 + kk];
        float2 bv = *(const float2*)&b1[kk];
        hib[i2][kk] = hv.x + bv.x; hib[i2][kk + 1] = hv.y + bv.y;
    }
    if (tid < 64) *(float4*)&csv[tid * 4] = *(const float4*)&c[tid * 4];

    STAGE_HJ(0, 0);
    __syncthreads();
    const float bpw = bpv[p];
    STAGE_HJ(1, 1);
    BUILD_P(0, 0);
    __syncthreads();

    f32x4 acc[4][4] = {};

#pragma unroll
    for (int kt = 0; kt < 8; ++kt) {
        const int cur = kt & 1;
        if (kt < 6) STAGE_HJ(kt + 2, cur);
        short8 bh[4], bl[4];
#pragma unroll
        for (int nf = 0; nf < 4; ++nf) {
            int col = wn0 + nf * 16 + ln;
            long bo = (long)col * 256 + kt * 32 + g * 8;
            bh[nf] = *(const short8*)(w2th + bo);
            bl[nf] = *(const short8*)(w2tl + bo);
        }
        if (kt < 7) BUILD_P(kt + 1, cur ^ 1);
        short8 ah[4], al[4];
#pragma unroll
        for (int mf = 0; mf < 4; ++mf) {
            int row = wm0 + mf * 16 + ln;
            int off = (row * 64 + g * 16) ^ ((row & 7) << 4);
            ah[mf] = *(const short8*)((const char*)&Ph[cur][0] + off);
            al[mf] = *(const short8*)((const char*)&Pl[cur][0] + off);
        }
#pragma unroll
        for (int mf = 0; mf < 4; ++mf)
#pragma unroll
            for (int nf = 0; nf < 4; ++nf) {
                acc[mf][nf] = MFMA16(ah[mf], bh[nf], acc[mf][nf]);
                acc[mf][nf] = MFMA16(ah[mf], bl[nf], acc[mf][nf]);
                acc[mf][nf] = MFMA16(al[mf], bh[nf], acc[mf][nf]);
            }
        __syncthreads();
    }

    float b2v[4], w3v[4];
#pragma unroll
    for (int nf = 0; nf < 4; ++nf) {
        int col = wn0 + nf * 16 + ln;
        b2v[nf] = b2[col];
        w3v[nf] = w3[col];
    }
#pragma unroll
    for (int mf = 0; mf < 4; ++mf) {
#pragma unroll
        for (int r = 0; r < 4; ++r) {
            float s = 0.f;
#pragma unroll
            for (int nf = 0; nf < 4; ++nf)
                s += fmaxf(acc[mf][nf][r] + b2v[nf], 0.f) * w3v[nf];
            s += __shfl_xor(s, 1, 64);
            s += __shfl_xor(s, 2, 64);
            s += __shfl_xor(s, 4, 64);
            s += __shfl_xor(s, 8, 64);
            if (ln == 0)
                red[wm0 + mf * 16 + g * 4 + r][wid >> 1] = s;
        }
    }
    __syncthreads();
    if (tid < 128) {
        int i = ib0 + (tid >> 6), j = j0 + (tid & 63);
        out[((long)(b * 256 + i)) * 256 + j] = red[tid][0] + red[tid][1] + b3[0];
    }
}

// ---------------------------------------------------------------------------
extern "C" void kernel_launch(void* const* d_in, const int* in_sizes, int n_in,
                              void* d_out, int out_size, void* d_ws, size_t ws_size,
                              hipStream_t stream)
{
    const float* emb   = (const float*)d_in[0];
    const float* bp    = (const float*)d_in[1];
    const float* ew1   = (const float*)d_in[3];
    const float* eb1   = (const float*)d_in[4];
    const float* ew2   = (const float*)d_in[5];
    const float* eb2   = (const float*)d_in[6];
    const float* wself = (const float*)d_in[7];
    const float* bself = (const float*)d_in[8];
    const float* wedge = (const float*)d_in[9];
    const float* bedge = (const float*)d_in[10];
    const float* lng   = (const float*)d_in[11];
    const float* lnb   = (const float*)d_in[12];
    const float* mw1   = (const float*)d_in[13];
    const float* mb1   = (const float*)d_in[14];
    const float* mw2   = (const float*)d_in[15];
    const float* mb2   = (const float*)d_in[16];
    const float* mw3   = (const float*)d_in[17];
    const float* mb3   = (const float*)d_in[18];
    float* out = (float*)d_out;

    float* ws = (float*)d_ws;
    float* h1  = ws;               // 524288 (enc hidden)
    float* hA  = h1 + 524288;      // 262144
    float* hB  = hA + 262144;      // 262144
    float* egA = hB + 262144;      // 262144
    float* egB = egA + 262144;     // 262144
    float* hi  = egB + 262144;     // 262144
    float* hj  = hi + 262144;      // 262144
    short* w2th = (short*)(hj + 262144);   // 32768 shorts
    short* w2tl = w2th + 32768;            // 32768 shorts

    dim3 blk(256);

    // 1. enc1 (tiled, relu) + w2 transpose/split side-job
    gemm_s<true, false, true><<<dim3(16, 40), blk, 0, stream>>>(emb, ew1, eb1, h1,
        nullptr, nullptr, nullptr, nullptr, nullptr, nullptr,
        1024, 512, 640, 0, mw2, w2th, w2tl);

    // 2. enc2 + eg0
    enc2_fuse<<<dim3(256), blk, 0, stream>>>(h1, ew2, eb2, wedge, bedge, hA, egA);

    // 3-5. GCN layers, each one dispatch
    layer_fuse<false><<<dim3(256), blk, 0, stream>>>(hA, bp, egA,
        wself, bself, lng, lnb,
        wedge + 65536, bedge + 256, nullptr, hB, egB, nullptr);
    layer_fuse<false><<<dim3(256), blk, 0, stream>>>(hB, bp, egB,
        wself + 65536, bself + 256, lng + 256, lnb + 256,
        wedge + 131072, bedge + 512, nullptr, hA, egA, nullptr);
    layer_fuse<true><<<dim3(256), blk, 0, stream>>>(hA, bp, egA,
        wself + 131072, bself + 512, lng + 512, lnb + 512,
        mw1, nullptr, mw1 + 65536, hB, hi, hj);

    // 6. pairwise MFMA scorer
    pairwise4<<<dim3(4, 128, 4), blk, 0, stream>>>(hi, hj, bp,
        mw1 + 131072, mb1, w2th, w2tl, mb2, mw3, mb3, out);
}